// Round 1
// baseline (364.875 us; speedup 1.0000x reference)
//
#include <hip/hip_runtime.h>

// DiffAttn forward, MI355X/gfx950. All heavy math in bf16 MFMA, f32 softmax/LN.
// ws layout (u16 units, SZ = 2048*2048):
//   xb, Wqt, Wkt, Wvt, Wot, Qb, Kb, Vtb, Mb  -> 9*8MB = 72MB

typedef unsigned short u16;
typedef __attribute__((ext_vector_type(4))) float f32x4;
typedef __attribute__((ext_vector_type(8))) short bf16x8;

#define LAMBDA_INIT  0.7836057665317954f
#define ONE_MINUS_LI 0.2163942334682046f

__device__ __forceinline__ u16 f2bf(float f) {
    union { float f; unsigned u; } v; v.f = f;
    unsigned r = v.u + 0x7FFFu + ((v.u >> 16) & 1u);   // RNE
    return (u16)(r >> 16);
}

__device__ __forceinline__ void gld_lds16(const u16* g, u16* l) {
    __builtin_amdgcn_global_load_lds((const __attribute__((address_space(1))) void*)g,
                                     (__attribute__((address_space(3))) void*)l, 16, 0, 0);
}

// ---------------- cast x (f32 -> bf16), 4M elements ----------------
__global__ void cast_f32_bf16(const float* __restrict__ in, u16* __restrict__ out) {
    int i = (blockIdx.x * 256 + threadIdx.x) * 4;
    float4 v = *(const float4*)(in + i);
    ushort4 o;
    o.x = f2bf(v.x); o.y = f2bf(v.y); o.z = f2bf(v.z); o.w = f2bf(v.w);
    *(ushort4*)(out + i) = o;
}

// ---------------- transpose + cast W (2048x2048 f32 -> Wt bf16 [n][k]) ----------------
__global__ void transpose_cast(const float* __restrict__ W, u16* __restrict__ Wt) {
    __shared__ float tile[32][33];
    const int c0 = blockIdx.x * 32, r0 = blockIdx.y * 32;
    const int tx = threadIdx.x, ty = threadIdx.y;  // (32,8)
#pragma unroll
    for (int i = 0; i < 32; i += 8) tile[ty + i][tx] = W[(r0 + ty + i) * 2048 + c0 + tx];
    __syncthreads();
#pragma unroll
    for (int i = 0; i < 32; i += 8) Wt[(c0 + ty + i) * 2048 + r0 + tx] = f2bf(tile[tx][ty + i]);
}

// ---------------- GEMM: C[m][n] = scale * sum_k A[m][k]*B[n][k]  (A,B bf16) ----------------
// 128x128 tile, BK=32, 4 waves, global_load_lds staging.
template <int OUT_F32>
__global__ __launch_bounds__(256, 2) void gemm_bt(const u16* __restrict__ A, const u16* __restrict__ B,
                                                  void* __restrict__ Cout, int N, int K, float scale) {
    __shared__ __align__(16) u16 As[128 * 32];
    __shared__ __align__(16) u16 Bs[128 * 32];
    const int tid = threadIdx.x;
    const int m0 = blockIdx.y * 128, n0 = blockIdx.x * 128;
    const int lane = tid & 63, w = tid >> 6;
    const int wr = w >> 1, wc = w & 1;
    const int q16 = lane & 15, g = lane >> 4;
    const f32x4 fzero = {0.f, 0.f, 0.f, 0.f};
    f32x4 acc[4][4];
#pragma unroll
    for (int m = 0; m < 4; m++)
#pragma unroll
        for (int n = 0; n < 4; n++) acc[m][n] = fzero;

    for (int kb = 0; kb < K; kb += 32) {
        __syncthreads();
#pragma unroll
        for (int p = 0; p < 2; p++) {
            int s = p * 256 + tid;  // 512 16B segs per tile; lds addr = s*16 (lane-stride-16 ok)
            gld_lds16(A + (m0 + (s >> 2)) * K + kb + 8 * (s & 3), As + s * 8);
            gld_lds16(B + (n0 + (s >> 2)) * K + kb + 8 * (s & 3), Bs + s * 8);
        }
        __syncthreads();
        bf16x8 af[4], bfr[4];
#pragma unroll
        for (int m = 0; m < 4; m++) af[m] = *(const bf16x8*)(As + (wr * 64 + m * 16 + q16) * 32 + 8 * g);
#pragma unroll
        for (int n = 0; n < 4; n++) bfr[n] = *(const bf16x8*)(Bs + (wc * 64 + n * 16 + q16) * 32 + 8 * g);
#pragma unroll
        for (int m = 0; m < 4; m++)
#pragma unroll
            for (int n = 0; n < 4; n++)
                acc[m][n] = __builtin_amdgcn_mfma_f32_16x16x32_bf16(af[m], bfr[n], acc[m][n], 0, 0, 0);
    }
#pragma unroll
    for (int m = 0; m < 4; m++)
#pragma unroll
        for (int n = 0; n < 4; n++) {
            int row = m0 + wr * 64 + m * 16 + 4 * g;
            int col = n0 + wc * 64 + n * 16 + q16;
#pragma unroll
            for (int r = 0; r < 4; r++) {
                float v = acc[m][n][r] * scale;
                if (OUT_F32) ((float*)Cout)[(row + r) * N + col] = v;
                else         ((u16*)Cout)[(row + r) * N + col] = f2bf(v);
            }
        }
}

// ---------------- fused dual-stream causal flash attention + diff + subLN + scatter to M ----------------
// grid (32, 16): x = q-block (64 rows), y = head pair. 4 waves, 16 q-rows each.
// Qb,Kb: [2048][2048] bf16 (Q pre-scaled by hd^-0.5). Vtb: [2048][2048] bf16, Vt[c][t] = V[t][c].
// M[h*128 + t/16][(t%16)*128 + d] = LN(O1/l1 - lam*O2/l2) * (1-LAMBDA_INIT)
__global__ __launch_bounds__(256, 2) void diff_attn(const u16* __restrict__ Qb, const u16* __restrict__ Kb,
                                                    const u16* __restrict__ Vt, u16* __restrict__ Mb,
                                                    const float* __restrict__ lq1, const float* __restrict__ lk1,
                                                    const float* __restrict__ lq2, const float* __restrict__ lk2) {
    __shared__ __align__(16) char smem[40960];
    u16* K1s = (u16*)smem;                  // [64][64]
    u16* K2s = (u16*)smem + 4096;           // [64][64]
    u16* Vts = (u16*)smem + 8192;           // [128][64]  (V^T block: [d][k])
    u16* Pw = (u16*)(smem + 32768) + (threadIdx.x >> 6) * 1024;  // per-wave P [16 q][64 k]

    const int tid = threadIdx.x;
    const int lane = tid & 63, w = tid >> 6;
    const int q16 = lane & 15, g = lane >> 4;
    const int h = blockIdx.y;
    const int q0 = blockIdx.x * 64;
    const int qg = q0 + 16 * w + q16;  // this lane's query row

    float sl1 = 0.f, sl2 = 0.f;
    for (int i = 0; i < 64; i++) { sl1 += lq1[i] * lk1[i]; sl2 += lq2[i] * lk2[i]; }
    const float lam = expf(sl1) - expf(sl2) + LAMBDA_INIT;

    // Q fragments (both streams), contiguous-k 16B loads
    bf16x8 qf[2][2];
#pragma unroll
    for (int st = 0; st < 2; st++)
#pragma unroll
        for (int db = 0; db < 2; db++)
            qf[st][db] = *(const bf16x8*)(Qb + qg * 2048 + (2 * h + st) * 64 + db * 32 + 8 * g);

    const f32x4 fzero = {0.f, 0.f, 0.f, 0.f};
    f32x4 Oacc[2][8];
#pragma unroll
    for (int st = 0; st < 2; st++)
#pragma unroll
        for (int dt = 0; dt < 8; dt++) Oacc[st][dt] = fzero;
    float mrun0 = -__builtin_inff(), mrun1 = -__builtin_inff();
    float den0 = 0.f, den1 = 0.f;

    const int kend = q0 + 64;  // causal: k-blocks 0..q0
    for (int kb = 0; kb < kend; kb += 64) {
        __syncthreads();
#pragma unroll
        for (int p = 0; p < 2; p++) {
            int s = p * 256 + tid;  // K blocks: 64 rows x 64 bf16 = 512 segs
            gld_lds16(Kb + (kb + (s >> 3)) * 2048 + (2 * h) * 64 + 8 * (s & 7), K1s + s * 8);
            gld_lds16(Kb + (kb + (s >> 3)) * 2048 + (2 * h + 1) * 64 + 8 * (s & 7), K2s + s * 8);
        }
#pragma unroll
        for (int p = 0; p < 4; p++) {
            int s = p * 256 + tid;  // V^T block: 128 rows x 64 bf16 = 1024 segs
            gld_lds16(Vt + (128 * h + (s >> 3)) * 2048 + kb + 8 * (s & 7), Vts + s * 8);
        }
        __syncthreads();

#pragma unroll
        for (int st = 0; st < 2; st++) {
            const u16* Ks = st ? K2s : K1s;
            float mrun = st ? mrun1 : mrun0;
            float den = st ? den1 : den0;
            // S^T tiles: D[k][q] = K x Q^T
            f32x4 sc[4];
#pragma unroll
            for (int kt = 0; kt < 4; kt++) {
                bf16x8 kf0 = *(const bf16x8*)(Ks + (kt * 16 + q16) * 64 + 8 * g);
                bf16x8 kf1 = *(const bf16x8*)(Ks + (kt * 16 + q16) * 64 + 32 + 8 * g);
                f32x4 a = __builtin_amdgcn_mfma_f32_16x16x32_bf16(kf0, qf[st][0], fzero, 0, 0, 0);
                a = __builtin_amdgcn_mfma_f32_16x16x32_bf16(kf1, qf[st][1], a, 0, 0, 0);
                sc[kt] = a;
            }
            // causal mask + row max (row = q; values spread over lane group {q,q+16,q+32,q+48})
            float lm = -__builtin_inff();
#pragma unroll
            for (int kt = 0; kt < 4; kt++)
#pragma unroll
                for (int r = 0; r < 4; r++) {
                    int kg = kb + kt * 16 + 4 * g + r;
                    float v = (kg <= qg) ? sc[kt][r] : -__builtin_inff();
                    sc[kt][r] = v;
                    lm = fmaxf(lm, v);
                }
            lm = fmaxf(lm, __shfl_xor(lm, 16));
            lm = fmaxf(lm, __shfl_xor(lm, 32));
            float mnew = fmaxf(mrun, lm);
            float alpha = __expf(mrun - mnew);
            float ps = 0.f;
#pragma unroll
            for (int kt = 0; kt < 4; kt++) {
                float p0 = __expf(sc[kt][0] - mnew);
                float p1 = __expf(sc[kt][1] - mnew);
                float p2 = __expf(sc[kt][2] - mnew);
                float p3 = __expf(sc[kt][3] - mnew);
                ps += (p0 + p1) + (p2 + p3);
                unsigned lo = (unsigned)f2bf(p0) | ((unsigned)f2bf(p1) << 16);
                unsigned hi = (unsigned)f2bf(p2) | ((unsigned)f2bf(p3) << 16);
                *(unsigned*)(Pw + q16 * 64 + kt * 16 + 4 * g) = lo;
                *(unsigned*)(Pw + q16 * 64 + kt * 16 + 4 * g + 2) = hi;
            }
            ps += __shfl_xor(ps, 16);
            ps += __shfl_xor(ps, 32);
            den = den * alpha + ps;
            mrun = mnew;
#pragma unroll
            for (int dt = 0; dt < 8; dt++) Oacc[st][dt] *= alpha;
            // PV: O^T = V^T x P^T
#pragma unroll
            for (int kh = 0; kh < 2; kh++) {
                bf16x8 pf = *(const bf16x8*)(Pw + q16 * 64 + kh * 32 + 8 * g);
#pragma unroll
                for (int dt = 0; dt < 8; dt++) {
                    bf16x8 vf = *(const bf16x8*)(Vts + (dt * 16 + q16) * 64 + kh * 32 + 8 * g);
                    Oacc[st][dt] = __builtin_amdgcn_mfma_f32_16x16x32_bf16(vf, pf, Oacc[st][dt], 0, 0, 0);
                }
            }
            if (st) { mrun1 = mrun; den1 = den; } else { mrun0 = mrun; den0 = den; }
        }
    }

    // epilogue: diff, LN over 128 dims (spread over lane group), scatter-free M write
    const float i1 = 1.f / den0;
    const float i2 = lam / den1;
    float S1 = 0.f, S2 = 0.f;
#pragma unroll
    for (int dt = 0; dt < 8; dt++)
#pragma unroll
        for (int r = 0; r < 4; r++) {
            float v = Oacc[0][dt][r] * i1 - Oacc[1][dt][r] * i2;
            S1 += v; S2 += v * v;
        }
    S1 += __shfl_xor(S1, 16); S1 += __shfl_xor(S1, 32);
    S2 += __shfl_xor(S2, 16); S2 += __shfl_xor(S2, 32);
    const float mu = S1 * (1.f / 128.f);
    const float var = S2 * (1.f / 128.f) - mu * mu;
    const float rs = rsqrtf(var + 1e-5f) * ONE_MINUS_LI;

    __syncthreads();  // done with K/V LDS across all waves
    float* Ot = (float*)smem + w * 2048;  // per-wave [16 q][128 d] f32
#pragma unroll
    for (int dt = 0; dt < 8; dt++)
#pragma unroll
        for (int r = 0; r < 4; r++) {
            float v = Oacc[0][dt][r] * i1 - Oacc[1][dt][r] * i2;
            Ot[q16 * 128 + dt * 16 + 4 * g + r] = (v - mu) * rs;
        }
    __syncthreads();
    // wave w owns t in [q0+16w, q0+16w+16): M row R constant per wave, fully coalesced row write
    const int R = h * 128 + q0 / 16 + w;
    const int qr = lane >> 2, dc = (lane & 3) * 32;
    const float* src = (const float*)smem + w * 2048 + qr * 128 + dc;
    u16* dst = Mb + R * 2048 + qr * 128 + dc;
#pragma unroll
    for (int c = 0; c < 4; c++) {
        f32x4 a = *(const f32x4*)(src + 8 * c);
        f32x4 b = *(const f32x4*)(src + 8 * c + 4);
        int4 o;
        o.x = (int)((unsigned)f2bf(a[0]) | ((unsigned)f2bf(a[1]) << 16));
        o.y = (int)((unsigned)f2bf(a[2]) | ((unsigned)f2bf(a[3]) << 16));
        o.z = (int)((unsigned)f2bf(b[0]) | ((unsigned)f2bf(b[1]) << 16));
        o.w = (int)((unsigned)f2bf(b[2]) | ((unsigned)f2bf(b[3]) << 16));
        *(int4*)(dst + 8 * c) = o;
    }
}

extern "C" void kernel_launch(void* const* d_in, const int* in_sizes, int n_in,
                              void* d_out, int out_size, void* d_ws, size_t ws_size,
                              hipStream_t stream) {
    (void)in_sizes; (void)n_in; (void)out_size; (void)ws_size;
    const float* x = (const float*)d_in[0];
    const float* Wq = (const float*)d_in[1];
    const float* Wk = (const float*)d_in[2];
    const float* Wv = (const float*)d_in[3];
    const float* Wo = (const float*)d_in[4];
    const float* lq1 = (const float*)d_in[5];
    const float* lk1 = (const float*)d_in[6];
    const float* lq2 = (const float*)d_in[7];
    const float* lk2 = (const float*)d_in[8];

    u16* ws = (u16*)d_ws;
    const size_t SZ = 2048u * 2048u;
    u16* xb = ws;
    u16* Wqt = ws + SZ;
    u16* Wkt = ws + 2 * SZ;
    u16* Wvt = ws + 3 * SZ;
    u16* Wot = ws + 4 * SZ;
    u16* Qb = ws + 5 * SZ;
    u16* Kb = ws + 6 * SZ;
    u16* Vtb = ws + 7 * SZ;
    u16* Mb = ws + 8 * SZ;

    cast_f32_bf16<<<4096, 256, 0, stream>>>(x, xb);
    dim3 tg(64, 64), tb(32, 8);
    transpose_cast<<<tg, tb, 0, stream>>>(Wq, Wqt);
    transpose_cast<<<tg, tb, 0, stream>>>(Wk, Wkt);
    transpose_cast<<<tg, tb, 0, stream>>>(Wv, Wvt);
    transpose_cast<<<tg, tb, 0, stream>>>(Wo, Wot);

    dim3 gg(16, 16);
    // Q = 0.125 * x @ Wq ; K = x @ Wk ; Vt = (x @ Wv)^T  (via Wv^T @ x^T, lands row-major)
    gemm_bt<0><<<gg, 256, 0, stream>>>(xb, Wqt, Qb, 2048, 2048, 0.125f);
    gemm_bt<0><<<gg, 256, 0, stream>>>(xb, Wkt, Kb, 2048, 2048, 1.0f);
    gemm_bt<0><<<gg, 256, 0, stream>>>(Wvt, xb, Vtb, 2048, 2048, 1.0f);

    dim3 ag(32, 16);
    diff_attn<<<ag, 256, 0, stream>>>(Qb, Kb, Vtb, Mb, lq1, lk1, lq2, lk2);

    gemm_bt<1><<<gg, 256, 0, stream>>>(Mb, Wot, d_out, 2048, 2048, 1.0f);
}

// Round 2
// 235.270 us; speedup vs baseline: 1.5509x; 1.5509x over previous
//
#include <hip/hip_runtime.h>

// DiffAttn forward, MI355X/gfx950. bf16 MFMA everywhere, f32 softmax/LN.
// ws layout (u16 units, SZ = 2048*2048):
//   xb, Wqt, Wkt, Wvt, Wot, Qb, Kb, Vtb, Mb  -> 9*8MB = 72MB

typedef unsigned short u16;
typedef __attribute__((ext_vector_type(4))) float f32x4;
typedef __attribute__((ext_vector_type(8))) short bf16x8;

#define LAMBDA_INIT  0.7836057665317954f
#define ONE_MINUS_LI 0.2163942334682046f

__device__ __forceinline__ u16 f2bf(float f) {
    union { float f; unsigned u; } v; v.f = f;
    unsigned r = v.u + 0x7FFFu + ((v.u >> 16) & 1u);   // RNE
    return (u16)(r >> 16);
}

__device__ __forceinline__ void gld_lds16(const u16* g, u16* l) {
    __builtin_amdgcn_global_load_lds((const __attribute__((address_space(1))) void*)g,
                                     (__attribute__((address_space(3))) void*)l, 16, 0, 0);
}

// ---------------- cast x (f32 -> bf16), 4M elements ----------------
__global__ void cast_f32_bf16(const float* __restrict__ in, u16* __restrict__ out) {
    int i = (blockIdx.x * 256 + threadIdx.x) * 4;
    float4 v = *(const float4*)(in + i);
    ushort4 o;
    o.x = f2bf(v.x); o.y = f2bf(v.y); o.z = f2bf(v.z); o.w = f2bf(v.w);
    *(ushort4*)(out + i) = o;
}

// ---------------- transpose + cast 4x W (2048x2048 f32 -> Wt bf16 [n][k]) ----------------
__global__ void transpose_cast4(const float* __restrict__ W0, const float* __restrict__ W1,
                                const float* __restrict__ W2, const float* __restrict__ W3,
                                u16* __restrict__ O0, u16* __restrict__ O1,
                                u16* __restrict__ O2, u16* __restrict__ O3) {
    __shared__ float tile[32][33];
    const int z = blockIdx.z;
    const float* W = z == 0 ? W0 : z == 1 ? W1 : z == 2 ? W2 : W3;
    u16* Wt = z == 0 ? O0 : z == 1 ? O1 : z == 2 ? O2 : O3;
    const int c0 = blockIdx.x * 32, r0 = blockIdx.y * 32;
    const int tx = threadIdx.x, ty = threadIdx.y;  // (32,8)
#pragma unroll
    for (int i = 0; i < 32; i += 8) tile[ty + i][tx] = W[(r0 + ty + i) * 2048 + c0 + tx];
    __syncthreads();
#pragma unroll
    for (int i = 0; i < 32; i += 8) Wt[(c0 + ty + i) * 2048 + r0 + tx] = f2bf(tile[tx][ty + i]);
}

// ---------------- GEMM: C[m][n] = scale * sum_k A[m][k]*B[n][k]  (A,B bf16) ----------------
// 128x128 tile, BK=64, 4 waves, dbuf global_load_lds + XOR-swizzled LDS, counted vmcnt.
template <int OUT_F32>
__global__ __launch_bounds__(256, 2) void gemm_bt(const u16* __restrict__ A, const u16* __restrict__ B,
                                                  void* __restrict__ Cout, int N, int K, float scale) {
    __shared__ __align__(16) u16 As[2][128 * 64];
    __shared__ __align__(16) u16 Bs[2][128 * 64];
    const int tid = threadIdx.x;
    // chunked XCD swizzle: XCD k gets 32 consecutive flat tiles (2 m-panels)
    const int flat = ((blockIdx.x & 7) << 5) | (blockIdx.x >> 3);
    const int m0 = (flat >> 4) * 128, n0 = (flat & 15) * 128;
    const int lane = tid & 63, w = tid >> 6;
    const int wr = w >> 1, wc = w & 1;
    const int q16 = lane & 15, g = lane >> 4;
    const int sw = q16 & 7;
    const f32x4 fzero = {0.f, 0.f, 0.f, 0.f};
    f32x4 acc[4][4];
#pragma unroll
    for (int m = 0; m < 4; m++)
#pragma unroll
        for (int n = 0; n < 4; n++) acc[m][n] = fzero;

#define STAGE_G(buf, kb)                                                        \
    {                                                                           \
        _Pragma("unroll") for (int p = 0; p < 4; p++) {                         \
            int s = p * 256 + tid;                                              \
            int row = s >> 3, sg = (s ^ row) & 7;                               \
            gld_lds16(A + (size_t)(m0 + row) * K + (kb) + sg * 8, As[buf] + s * 8); \
            gld_lds16(B + (size_t)(n0 + row) * K + (kb) + sg * 8, Bs[buf] + s * 8); \
        }                                                                       \
    }

    STAGE_G(0, 0);
    int cur = 0;
    for (int kb = 0; kb < K; kb += 64) {
        if (kb + 64 < K) {
            STAGE_G(cur ^ 1, kb + 64);
            asm volatile("s_waitcnt vmcnt(8)" ::: "memory");
        } else {
            asm volatile("s_waitcnt vmcnt(0)" ::: "memory");
        }
        __builtin_amdgcn_s_barrier();
        bf16x8 af[4][2], bfr[4][2];
#pragma unroll
        for (int m = 0; m < 4; m++) {
            const u16* ar = As[cur] + (wr * 64 + m * 16 + q16) * 64;
            af[m][0] = *(const bf16x8*)(ar + 8 * (g ^ sw));
            af[m][1] = *(const bf16x8*)(ar + 8 * ((4 + g) ^ sw));
        }
#pragma unroll
        for (int n = 0; n < 4; n++) {
            const u16* br = Bs[cur] + (wc * 64 + n * 16 + q16) * 64;
            bfr[n][0] = *(const bf16x8*)(br + 8 * (g ^ sw));
            bfr[n][1] = *(const bf16x8*)(br + 8 * ((4 + g) ^ sw));
        }
#pragma unroll
        for (int m = 0; m < 4; m++)
#pragma unroll
            for (int n = 0; n < 4; n++) {
                acc[m][n] = __builtin_amdgcn_mfma_f32_16x16x32_bf16(af[m][0], bfr[n][0], acc[m][n], 0, 0, 0);
                acc[m][n] = __builtin_amdgcn_mfma_f32_16x16x32_bf16(af[m][1], bfr[n][1], acc[m][n], 0, 0, 0);
            }
        asm volatile("s_waitcnt lgkmcnt(0)" ::: "memory");
        __builtin_amdgcn_s_barrier();
        cur ^= 1;
    }
#pragma unroll
    for (int m = 0; m < 4; m++)
#pragma unroll
        for (int n = 0; n < 4; n++) {
            int row = m0 + wr * 64 + m * 16 + 4 * g;
            int col = n0 + wc * 64 + n * 16 + q16;
#pragma unroll
            for (int r = 0; r < 4; r++) {
                float v = acc[m][n][r] * scale;
                if (OUT_F32) ((float*)Cout)[(size_t)(row + r) * N + col] = v;
                else         ((u16*)Cout)[(size_t)(row + r) * N + col] = f2bf(v);
            }
        }
#undef STAGE_G
}

// ---------------- fused dual-stream causal flash attention + diff + subLN + scatter to M ----------------
// grid 512 1D; remap: XCD k owns heads {2k,2k+1}; q-blocks biggest-first.
// Qb,Kb: [2048][2048] bf16 (Q pre-scaled). Vt: [2048][2048] bf16, Vt[c][t] = V[t][c].
// M[h*128 + t/16][(t%16)*128 + d] = LN(O1/l1 - lam*O2/l2) * (1-LAMBDA_INIT)
__global__ __launch_bounds__(256, 2) void diff_attn(const u16* __restrict__ Qg, const u16* __restrict__ Kg,
                                                    const u16* __restrict__ Vg, u16* __restrict__ Mg,
                                                    const float* __restrict__ lq1, const float* __restrict__ lk1,
                                                    const float* __restrict__ lq2, const float* __restrict__ lk2) {
    // LDS (u16 units): Kbuf[2] 64x128 @0/@16384, Vbuf[2] 128x64 @8192/@24576, P @32768 (4 waves x 2 streams x 16x64)
    __shared__ __align__(16) u16 smem[40960];   // 80 KB -> 2 blocks/CU
    const int tid = threadIdx.x;
    const int lane = tid & 63, w = tid >> 6;
    const int q16 = lane & 15, g = lane >> 4;
    const int sw = q16 & 7;
    const int id = blockIdx.x;
    const int h = ((id & 7) << 1) | ((id >> 3) & 1);
    const int qi = 31 - (id >> 4);
    const int q0 = qi * 64;
    const int qg = q0 + 16 * w + q16;

    u16* Kb0 = smem;
    u16* Vb0 = smem + 8192;
    u16* Kb1 = smem + 16384;
    u16* Vb1 = smem + 24576;
    u16* Pw = smem + 32768 + w * 2048;  // [2 streams][16 q][64 k]

    // Q fragments (both streams)
    bf16x8 qf[2][2];
#pragma unroll
    for (int st = 0; st < 2; st++)
#pragma unroll
        for (int db = 0; db < 2; db++)
            qf[st][db] = *(const bf16x8*)(Qg + (size_t)qg * 2048 + 128 * h + 64 * st + 32 * db + 8 * g);

#define STAGE_K(dst, kb)                                                         \
    {                                                                            \
        _Pragma("unroll") for (int p = 0; p < 4; p++) {                          \
            int s = p * 256 + tid;                                               \
            int row = s >> 4, gc = s & 15;                                       \
            int sg = (gc & 8) | ((gc ^ row) & 7);                                \
            gld_lds16(Kg + (size_t)((kb) + row) * 2048 + 128 * h + sg * 8, (dst) + s * 8); \
        }                                                                        \
    }
#define STAGE_V(dst, kb)                                                         \
    {                                                                            \
        _Pragma("unroll") for (int p = 0; p < 4; p++) {                          \
            int s = p * 256 + tid;                                               \
            int row = s >> 3, sg = (s ^ row) & 7;                                \
            gld_lds16(Vg + (size_t)(128 * h + row) * 2048 + (kb) + sg * 8, (dst) + s * 8); \
        }                                                                        \
    }

    const f32x4 fzero = {0.f, 0.f, 0.f, 0.f};
    f32x4 Oacc[2][8];
#pragma unroll
    for (int st = 0; st < 2; st++)
#pragma unroll
        for (int dt = 0; dt < 8; dt++) Oacc[st][dt] = fzero;
    float mrun[2] = {-__builtin_inff(), -__builtin_inff()};
    float den[2] = {0.f, 0.f};

    const int nt = qi + 1;
    STAGE_K(Kb0, 0);
    STAGE_V(Vb0, 0);
    int cur = 0;
    for (int t = 0; t < nt; t++) {
        const int kb = t * 64;
        const u16* Ks = cur ? Kb1 : Kb0;
        const u16* Vs = cur ? Vb1 : Vb0;
        if (t + 1 < nt) {
            STAGE_K(cur ? Kb0 : Kb1, kb + 64);
            STAGE_V(cur ? Vb0 : Vb1, kb + 64);
            asm volatile("s_waitcnt vmcnt(8)" ::: "memory");
        } else {
            asm volatile("s_waitcnt vmcnt(0)" ::: "memory");
        }
        __builtin_amdgcn_s_barrier();

        // QK^T (S^T): D[k][q], both streams
        f32x4 sc[2][4];
#pragma unroll
        for (int st = 0; st < 2; st++)
#pragma unroll
            for (int kt = 0; kt < 4; kt++) {
                const u16* kr = Ks + (kt * 16 + q16) * 128;
                bf16x8 kf0 = *(const bf16x8*)(kr + 8 * (st * 8 + (g ^ sw)));
                bf16x8 kf1 = *(const bf16x8*)(kr + 8 * (st * 8 + ((4 + g) ^ sw)));
                f32x4 a = __builtin_amdgcn_mfma_f32_16x16x32_bf16(kf0, qf[st][0], fzero, 0, 0, 0);
                a = __builtin_amdgcn_mfma_f32_16x16x32_bf16(kf1, qf[st][1], a, 0, 0, 0);
                sc[st][kt] = a;
            }

        // softmax per stream (row = q over lane group {q16, +16, +32, +48})
#pragma unroll
        for (int st = 0; st < 2; st++) {
            float lm = -__builtin_inff();
#pragma unroll
            for (int kt = 0; kt < 4; kt++)
#pragma unroll
                for (int r = 0; r < 4; r++) {
                    int kgi = kb + kt * 16 + 4 * g + r;
                    float v = (kgi <= qg) ? sc[st][kt][r] : -__builtin_inff();
                    sc[st][kt][r] = v;
                    lm = fmaxf(lm, v);
                }
            lm = fmaxf(lm, __shfl_xor(lm, 16));
            lm = fmaxf(lm, __shfl_xor(lm, 32));
            const float mnew = fmaxf(mrun[st], lm);
            const float alpha = __expf(mrun[st] - mnew);
            float ps = 0.f;
            u16* Pst = Pw + st * 1024;
#pragma unroll
            for (int kt = 0; kt < 4; kt++) {
                float p0 = __expf(sc[st][kt][0] - mnew);
                float p1 = __expf(sc[st][kt][1] - mnew);
                float p2 = __expf(sc[st][kt][2] - mnew);
                float p3 = __expf(sc[st][kt][3] - mnew);
                ps += (p0 + p1) + (p2 + p3);
                uint2 pr;
                pr.x = (unsigned)f2bf(p0) | ((unsigned)f2bf(p1) << 16);
                pr.y = (unsigned)f2bf(p2) | ((unsigned)f2bf(p3) << 16);
                *(uint2*)(Pst + q16 * 64 + ((kt * 16 + 4 * g) ^ (8 * sw))) = pr;
            }
            ps += __shfl_xor(ps, 16);
            ps += __shfl_xor(ps, 32);
            den[st] = den[st] * alpha + ps;
            mrun[st] = mnew;
#pragma unroll
            for (int dt = 0; dt < 8; dt++) Oacc[st][dt] *= alpha;
        }

        // PV: O^T = V^T x P^T ; V fragments shared by both streams
        bf16x8 pf[2][2];
#pragma unroll
        for (int st = 0; st < 2; st++)
#pragma unroll
            for (int kh = 0; kh < 2; kh++)
                pf[st][kh] = *(const bf16x8*)(Pw + st * 1024 + q16 * 64 + ((kh * 32 + 8 * g) ^ (8 * sw)));
#pragma unroll
        for (int kh = 0; kh < 2; kh++)
#pragma unroll
            for (int dt = 0; dt < 8; dt++) {
                bf16x8 vf = *(const bf16x8*)(Vs + (dt * 16 + q16) * 64 + 8 * ((kh * 4 + g) ^ sw));
                Oacc[0][dt] = __builtin_amdgcn_mfma_f32_16x16x32_bf16(vf, pf[0][kh], Oacc[0][dt], 0, 0, 0);
                Oacc[1][dt] = __builtin_amdgcn_mfma_f32_16x16x32_bf16(vf, pf[1][kh], Oacc[1][dt], 0, 0, 0);
            }
        asm volatile("s_waitcnt lgkmcnt(0)" ::: "memory");
        __builtin_amdgcn_s_barrier();
        cur ^= 1;
    }
#undef STAGE_K
#undef STAGE_V

    // lambda (after loop: keeps vmcnt FIFO clean in the main loop)
    float sl1 = 0.f, sl2 = 0.f;
    for (int i = 0; i < 64; i++) { sl1 += lq1[i] * lk1[i]; sl2 += lq2[i] * lk2[i]; }
    const float lam = expf(sl1) - expf(sl2) + LAMBDA_INIT;

    // epilogue: diff, LN over 128 dims (lane group), direct coalesced-ish M write
    const float i1 = 1.f / den[0];
    const float i2 = lam / den[1];
    float S1 = 0.f, S2 = 0.f;
#pragma unroll
    for (int dt = 0; dt < 8; dt++)
#pragma unroll
        for (int r = 0; r < 4; r++) {
            float v = Oacc[0][dt][r] * i1 - Oacc[1][dt][r] * i2;
            S1 += v; S2 += v * v;
        }
    S1 += __shfl_xor(S1, 16); S1 += __shfl_xor(S1, 32);
    S2 += __shfl_xor(S2, 16); S2 += __shfl_xor(S2, 32);
    const float mu = S1 * (1.f / 128.f);
    const float var = S2 * (1.f / 128.f) - mu * mu;
    const float rs = rsqrtf(var + 1e-5f) * ONE_MINUS_LI;

    const int R = h * 128 + (q0 >> 4) + w;  // same for whole wave
    u16* drow = Mg + (size_t)R * 2048 + q16 * 128;
#pragma unroll
    for (int dt = 0; dt < 8; dt++) {
        float v0 = (Oacc[0][dt][0] * i1 - Oacc[1][dt][0] * i2 - mu) * rs;
        float v1 = (Oacc[0][dt][1] * i1 - Oacc[1][dt][1] * i2 - mu) * rs;
        float v2 = (Oacc[0][dt][2] * i1 - Oacc[1][dt][2] * i2 - mu) * rs;
        float v3 = (Oacc[0][dt][3] * i1 - Oacc[1][dt][3] * i2 - mu) * rs;
        uint2 o;
        o.x = (unsigned)f2bf(v0) | ((unsigned)f2bf(v1) << 16);
        o.y = (unsigned)f2bf(v2) | ((unsigned)f2bf(v3) << 16);
        *(uint2*)(drow + dt * 16 + 4 * g) = o;
    }
}

extern "C" void kernel_launch(void* const* d_in, const int* in_sizes, int n_in,
                              void* d_out, int out_size, void* d_ws, size_t ws_size,
                              hipStream_t stream) {
    (void)in_sizes; (void)n_in; (void)out_size; (void)ws_size;
    const float* x = (const float*)d_in[0];
    const float* Wq = (const float*)d_in[1];
    const float* Wk = (const float*)d_in[2];
    const float* Wv = (const float*)d_in[3];
    const float* Wo = (const float*)d_in[4];
    const float* lq1 = (const float*)d_in[5];
    const float* lk1 = (const float*)d_in[6];
    const float* lq2 = (const float*)d_in[7];
    const float* lk2 = (const float*)d_in[8];

    u16* ws = (u16*)d_ws;
    const size_t SZ = 2048u * 2048u;
    u16* xb = ws;
    u16* Wqt = ws + SZ;
    u16* Wkt = ws + 2 * SZ;
    u16* Wvt = ws + 3 * SZ;
    u16* Wot = ws + 4 * SZ;
    u16* Qb = ws + 5 * SZ;
    u16* Kb = ws + 6 * SZ;
    u16* Vtb = ws + 7 * SZ;
    u16* Mb = ws + 8 * SZ;

    cast_f32_bf16<<<4096, 256, 0, stream>>>(x, xb);
    transpose_cast4<<<dim3(64, 64, 4), dim3(32, 8), 0, stream>>>(Wq, Wk, Wv, Wo, Wqt, Wkt, Wvt, Wot);

    // Q = 0.125 * x @ Wq ; K = x @ Wk ; Vt = (x @ Wv)^T  (via Wv^T as A, x as B)
    gemm_bt<0><<<256, 256, 0, stream>>>(xb, Wqt, Qb, 2048, 2048, 0.125f);
    gemm_bt<0><<<256, 256, 0, stream>>>(xb, Wkt, Kb, 2048, 2048, 1.0f);
    gemm_bt<0><<<256, 256, 0, stream>>>(Wvt, xb, Vtb, 2048, 2048, 1.0f);

    diff_attn<<<512, 256, 0, stream>>>(Qb, Kb, Vtb, Mb, lq1, lk1, lq2, lk2);

    gemm_bt<1><<<256, 256, 0, stream>>>(Mb, Wot, d_out, 2048, 2048, 1.0f);
}

// Round 4
// 176.979 us; speedup vs baseline: 2.0617x; 1.3294x over previous
//
#include <hip/hip_runtime.h>
#include <hip/hip_bf16.h>

// DiffAttn forward, MI355X/gfx950. bf16 MFMA everywhere, f32 softmax/LN.
// ws layout (u16 units, SZ = 2048*2048):
//   xb, Wqt, Wkt, Wvt, Wot, Qb, Kb, Vtb, Mb  -> 9*8MB = 72MB

typedef unsigned short u16;
typedef __attribute__((ext_vector_type(4))) float f32x4;
typedef __attribute__((ext_vector_type(8))) short bf16x8;

#define LAMBDA_INIT  0.7836057665317954f
#define ONE_MINUS_LI 0.2163942334682046f
// Q scale = hd^-0.5 * log2(e): QK^T lands pre-scaled for exp2-based softmax
#define QSCALE 0.18033688011112042f

// raw v_exp_f32 (exp2 semantics); avoids glibc __exp2f macro collision
#define EXP2F(x) __builtin_amdgcn_exp2f(x)

__device__ __forceinline__ u16 f2bf(float f) {
    union { float f; unsigned u; } v; v.f = f;
    unsigned r = v.u + 0x7FFFu + ((v.u >> 16) & 1u);   // RNE
    return (u16)(r >> 16);
}

// packed f32x2 -> bf16x2 (compiler emits v_cvt_pk_bf16_f32)
__device__ __forceinline__ unsigned pkbf(float a, float b) {
    union { __hip_bfloat162 h; unsigned u; } c;
    c.h = __float22bfloat162_rn(make_float2(a, b));
    return c.u;
}

__device__ __forceinline__ void gld_lds16(const u16* g, u16* l) {
    __builtin_amdgcn_global_load_lds((const __attribute__((address_space(1))) void*)g,
                                     (__attribute__((address_space(3))) void*)l, 16, 0, 0);
}

// ---------------- cast x (f32 -> bf16), 4M elements ----------------
__global__ void cast_f32_bf16(const float* __restrict__ in, u16* __restrict__ out) {
    int i = (blockIdx.x * 256 + threadIdx.x) * 4;
    float4 v = *(const float4*)(in + i);
    uint2 o;
    o.x = pkbf(v.x, v.y);
    o.y = pkbf(v.z, v.w);
    *(uint2*)(out + i) = o;
}

// ---------------- transpose + cast 4x W (2048x2048 f32 -> Wt bf16 [n][k]) ----------------
__global__ void transpose_cast4(const float* __restrict__ W0, const float* __restrict__ W1,
                                const float* __restrict__ W2, const float* __restrict__ W3,
                                u16* __restrict__ O0, u16* __restrict__ O1,
                                u16* __restrict__ O2, u16* __restrict__ O3) {
    __shared__ float tile[32][33];
    const int z = blockIdx.z;
    const float* W = z == 0 ? W0 : z == 1 ? W1 : z == 2 ? W2 : W3;
    u16* Wt = z == 0 ? O0 : z == 1 ? O1 : z == 2 ? O2 : O3;
    const int c0 = blockIdx.x * 32, r0 = blockIdx.y * 32;
    const int tx = threadIdx.x, ty = threadIdx.y;  // (32,8)
#pragma unroll
    for (int i = 0; i < 32; i += 8) tile[ty + i][tx] = W[(r0 + ty + i) * 2048 + c0 + tx];
    __syncthreads();
#pragma unroll
    for (int i = 0; i < 32; i += 8) Wt[(c0 + ty + i) * 2048 + r0 + tx] = f2bf(tile[tx][ty + i]);
}

// ---------------- GEMM core: C[m][n] = scale * sum_k A[m][k]*B[n][k], all dims 2048 ----------------
// 128x64 tile, BK=64, 4 waves (each 32x64), dbuf gld_lds + XOR swizzle, counted vmcnt. 48KB LDS -> 3 blocks/CU.
template <int OUT_F32>
__device__ __forceinline__ void gemm_core(const u16* __restrict__ A, const u16* __restrict__ B,
                                          void* __restrict__ Cout, float scale, int m0, int n0) {
    __shared__ __align__(16) u16 As[2][128 * 64];
    __shared__ __align__(16) u16 Bs[2][64 * 64];
    const int tid = threadIdx.x;
    const int lane = tid & 63, w = tid >> 6;
    const int q16 = lane & 15, g = lane >> 4;
    const int sw = q16 & 7;
    const f32x4 fzero = {0.f, 0.f, 0.f, 0.f};
    f32x4 acc[2][4];
#pragma unroll
    for (int m = 0; m < 2; m++)
#pragma unroll
        for (int n = 0; n < 4; n++) acc[m][n] = fzero;

#define STG(buf, kb)                                                                 \
    {                                                                                \
        _Pragma("unroll") for (int p = 0; p < 4; p++) {                              \
            int s = p * 256 + tid;  /* A: 1024 granules */                           \
            int row = s >> 3, sg = (s ^ row) & 7;                                    \
            gld_lds16(A + (size_t)(m0 + row) * 2048 + (kb) + sg * 8, As[buf] + s * 8); \
        }                                                                            \
        _Pragma("unroll") for (int p = 0; p < 2; p++) {                              \
            int s = p * 256 + tid;  /* B: 512 granules */                            \
            int row = s >> 3, sg = (s ^ row) & 7;                                    \
            gld_lds16(B + (size_t)(n0 + row) * 2048 + (kb) + sg * 8, Bs[buf] + s * 8); \
        }                                                                            \
    }

    STG(0, 0);
    int cur = 0;
    for (int kb = 0; kb < 2048; kb += 64) {
        if (kb + 64 < 2048) {
            STG(cur ^ 1, kb + 64);
            asm volatile("s_waitcnt vmcnt(6)" ::: "memory");
        } else {
            asm volatile("s_waitcnt vmcnt(0)" ::: "memory");
        }
        __builtin_amdgcn_s_barrier();
        bf16x8 af[2][2], bfr[4][2];
#pragma unroll
        for (int m = 0; m < 2; m++) {
            const u16* ar = As[cur] + (w * 32 + m * 16 + q16) * 64;
            af[m][0] = *(const bf16x8*)(ar + 8 * (g ^ sw));
            af[m][1] = *(const bf16x8*)(ar + 8 * ((4 + g) ^ sw));
        }
#pragma unroll
        for (int n = 0; n < 4; n++) {
            const u16* br = Bs[cur] + (n * 16 + q16) * 64;
            bfr[n][0] = *(const bf16x8*)(br + 8 * (g ^ sw));
            bfr[n][1] = *(const bf16x8*)(br + 8 * ((4 + g) ^ sw));
        }
        __builtin_amdgcn_s_setprio(1);
#pragma unroll
        for (int m = 0; m < 2; m++)
#pragma unroll
            for (int n = 0; n < 4; n++) {
                acc[m][n] = __builtin_amdgcn_mfma_f32_16x16x32_bf16(af[m][0], bfr[n][0], acc[m][n], 0, 0, 0);
                acc[m][n] = __builtin_amdgcn_mfma_f32_16x16x32_bf16(af[m][1], bfr[n][1], acc[m][n], 0, 0, 0);
            }
        __builtin_amdgcn_s_setprio(0);
        asm volatile("s_waitcnt lgkmcnt(0)" ::: "memory");
        __builtin_amdgcn_s_barrier();
        cur ^= 1;
    }
#pragma unroll
    for (int m = 0; m < 2; m++)
#pragma unroll
        for (int n = 0; n < 4; n++) {
            int row = m0 + w * 32 + m * 16 + 4 * g;
            int col = n0 + n * 16 + q16;
#pragma unroll
            for (int r = 0; r < 4; r++) {
                float v = acc[m][n][r] * scale;
                if (OUT_F32) ((float*)Cout)[(size_t)(row + r) * 2048 + col] = v;
                else         ((u16*)Cout)[(size_t)(row + r) * 2048 + col] = f2bf(v);
            }
        }
#undef STG
}

// fused Q/K/V projections: 1536 blocks (3 GEMMs x 512 tiles of 128x64)
__global__ __launch_bounds__(256, 3) void gemm_qkv(const u16* __restrict__ xb,
                                                   const u16* __restrict__ Wqt, const u16* __restrict__ Wkt,
                                                   const u16* __restrict__ Wvt,
                                                   u16* __restrict__ Qb, u16* __restrict__ Kb,
                                                   u16* __restrict__ Vtb) {
    const int id = blockIdx.x;
    const int ord = (id & 7) * 192 + (id >> 3);   // bijective XCD chunking (1536 % 8 == 0)
    const int which = ord / 512, r = ord & 511;
    const int m0 = (r & 15) * 128, n0 = (r >> 4) * 64;
    const u16 *A, *B; u16* C; float sc;
    if (which == 0)      { A = xb;  B = Wqt; C = Qb;  sc = QSCALE; }
    else if (which == 1) { A = xb;  B = Wkt; C = Kb;  sc = 1.f; }
    else                 { A = Wvt; B = xb;  C = Vtb; sc = 1.f; }
    gemm_core<0>(A, B, C, sc, m0, n0);
}

// final projection: 512 blocks
__global__ __launch_bounds__(256, 3) void gemm_out(const u16* __restrict__ Mb, const u16* __restrict__ Wot,
                                                   float* __restrict__ out) {
    const int id = blockIdx.x;
    const int ord = (id & 7) * 64 + (id >> 3);
    const int m0 = (ord & 15) * 128, n0 = (ord >> 4) * 64;
    gemm_core<1>(Mb, Wot, out, 1.f, m0, n0);
}

// ---------------- fused dual-stream causal flash attention + diff + subLN + scatter to M ----------------
// grid 512 1D; remap: XCD k owns heads {2k,2k+1}; q-blocks biggest-first.
// Qb,Kb: [2048][2048] bf16 (Q pre-scaled by hd^-0.5*log2e). Vt[c][t] = V[t][c].
// M[h*128 + t/16][(t%16)*128 + d] = LN(O1/l1 - lam*O2/l2) * (1-LAMBDA_INIT)
__global__ __launch_bounds__(256, 2) void diff_attn(const u16* __restrict__ Qg, const u16* __restrict__ Kg,
                                                    const u16* __restrict__ Vg, u16* __restrict__ Mg,
                                                    const float* __restrict__ lq1, const float* __restrict__ lk1,
                                                    const float* __restrict__ lq2, const float* __restrict__ lk2) {
    __shared__ __align__(16) u16 smem[40960];   // 80 KB -> 2 blocks/CU
    const int tid = threadIdx.x;
    const int lane = tid & 63, w = tid >> 6;
    const int q16 = lane & 15, g = lane >> 4;
    const int sw = q16 & 7;
    const int id = blockIdx.x;
    const int h = ((id & 7) << 1) | ((id >> 3) & 1);
    const int qi = 31 - (id >> 4);
    const int q0 = qi * 64;
    const int qg = q0 + 16 * w + q16;

    u16* Kb0 = smem;
    u16* Vb0 = smem + 8192;
    u16* Kb1 = smem + 16384;
    u16* Vb1 = smem + 24576;
    u16* Pw = smem + 32768 + w * 2048;  // [2 streams][16 q][64 k]

    bf16x8 qf[2][2];
#pragma unroll
    for (int st = 0; st < 2; st++)
#pragma unroll
        for (int db = 0; db < 2; db++)
            qf[st][db] = *(const bf16x8*)(Qg + (size_t)qg * 2048 + 128 * h + 64 * st + 32 * db + 8 * g);

#define STAGE_K(dst, kb)                                                         \
    {                                                                            \
        _Pragma("unroll") for (int p = 0; p < 4; p++) {                          \
            int s = p * 256 + tid;                                               \
            int row = s >> 4, gc = s & 15;                                       \
            int sg = (gc & 8) | ((gc ^ row) & 7);                                \
            gld_lds16(Kg + (size_t)((kb) + row) * 2048 + 128 * h + sg * 8, (dst) + s * 8); \
        }                                                                        \
    }
#define STAGE_V(dst, kb)                                                         \
    {                                                                            \
        _Pragma("unroll") for (int p = 0; p < 4; p++) {                          \
            int s = p * 256 + tid;                                               \
            int row = s >> 3, sg = (s ^ row) & 7;                                \
            gld_lds16(Vg + (size_t)(128 * h + row) * 2048 + (kb) + sg * 8, (dst) + s * 8); \
        }                                                                        \
    }

    const f32x4 fzero = {0.f, 0.f, 0.f, 0.f};
    f32x4 Oacc[2][8];
#pragma unroll
    for (int st = 0; st < 2; st++)
#pragma unroll
        for (int dt = 0; dt < 8; dt++) Oacc[st][dt] = fzero;
    float mrun[2] = {-__builtin_inff(), -__builtin_inff()};
    float den[2] = {0.f, 0.f};

    const int nt = qi + 1;
    STAGE_K(Kb0, 0);
    STAGE_V(Vb0, 0);
    int cur = 0;
    for (int t = 0; t < nt; t++) {
        const int kb = t * 64;
        const u16* Ks = cur ? Kb1 : Kb0;
        const u16* Vs = cur ? Vb1 : Vb0;
        if (t + 1 < nt) {
            STAGE_K(cur ? Kb0 : Kb1, kb + 64);
            STAGE_V(cur ? Vb0 : Vb1, kb + 64);
            asm volatile("s_waitcnt vmcnt(8)" ::: "memory");
        } else {
            asm volatile("s_waitcnt vmcnt(0)" ::: "memory");
        }
        __builtin_amdgcn_s_barrier();

        // QK^T (S^T): D[k][q], both streams
        f32x4 sc[2][4];
        __builtin_amdgcn_s_setprio(1);
#pragma unroll
        for (int st = 0; st < 2; st++)
#pragma unroll
            for (int kt = 0; kt < 4; kt++) {
                const u16* kr = Ks + (kt * 16 + q16) * 128;
                bf16x8 kf0 = *(const bf16x8*)(kr + 8 * (st * 8 + (g ^ sw)));
                bf16x8 kf1 = *(const bf16x8*)(kr + 8 * (st * 8 + ((4 + g) ^ sw)));
                f32x4 a = __builtin_amdgcn_mfma_f32_16x16x32_bf16(kf0, qf[st][0], fzero, 0, 0, 0);
                a = __builtin_amdgcn_mfma_f32_16x16x32_bf16(kf1, qf[st][1], a, 0, 0, 0);
                sc[st][kt] = a;
            }
        __builtin_amdgcn_s_setprio(0);

        const bool last = (t == nt - 1);
        // softmax per stream (row = q over lane group {q16, +16, +32, +48}); exp2 domain
#pragma unroll
        for (int st = 0; st < 2; st++) {
            float lm = -__builtin_inff();
            if (last) {  // only the diagonal tile needs masking
#pragma unroll
                for (int kt = 0; kt < 4; kt++)
#pragma unroll
                    for (int r = 0; r < 4; r++) {
                        int kgi = kb + kt * 16 + 4 * g + r;
                        float v = (kgi <= qg) ? sc[st][kt][r] : -__builtin_inff();
                        sc[st][kt][r] = v;
                        lm = fmaxf(lm, v);
                    }
            } else {
#pragma unroll
                for (int kt = 0; kt < 4; kt++)
#pragma unroll
                    for (int r = 0; r < 4; r++) lm = fmaxf(lm, sc[st][kt][r]);
            }
            lm = fmaxf(lm, __shfl_xor(lm, 16));
            lm = fmaxf(lm, __shfl_xor(lm, 32));
            const float mold = mrun[st];
            float mnew = mold;
            if (!__all(lm <= mold + 8.f)) {   // T13 defer-max: skip rescale if growth small
                mnew = fmaxf(mold, lm);
                const float alpha = EXP2F(mold - mnew);
                den[st] *= alpha;
#pragma unroll
                for (int dt = 0; dt < 8; dt++) Oacc[st][dt] *= alpha;
                mrun[st] = mnew;
            }
            float ps = 0.f;
            u16* Pst = Pw + st * 1024;
#pragma unroll
            for (int kt = 0; kt < 4; kt++) {
                float p0 = EXP2F(sc[st][kt][0] - mnew);
                float p1 = EXP2F(sc[st][kt][1] - mnew);
                float p2 = EXP2F(sc[st][kt][2] - mnew);
                float p3 = EXP2F(sc[st][kt][3] - mnew);
                ps += (p0 + p1) + (p2 + p3);
                uint2 pr;
                pr.x = pkbf(p0, p1);
                pr.y = pkbf(p2, p3);
                *(uint2*)(Pst + q16 * 64 + ((kt * 16 + 4 * g) ^ (8 * sw))) = pr;
            }
            ps += __shfl_xor(ps, 16);
            ps += __shfl_xor(ps, 32);
            den[st] += ps;
        }

        // PV: O^T = V^T x P^T ; V fragments shared by both streams
        bf16x8 pf[2][2];
#pragma unroll
        for (int st = 0; st < 2; st++)
#pragma unroll
            for (int kh = 0; kh < 2; kh++)
                pf[st][kh] = *(const bf16x8*)(Pw + st * 1024 + q16 * 64 + ((kh * 32 + 8 * g) ^ (8 * sw)));
        __builtin_amdgcn_s_setprio(1);
#pragma unroll
        for (int kh = 0; kh < 2; kh++)
#pragma unroll
            for (int dt = 0; dt < 8; dt++) {
                bf16x8 vf = *(const bf16x8*)(Vs + (dt * 16 + q16) * 64 + 8 * ((kh * 4 + g) ^ sw));
                Oacc[0][dt] = __builtin_amdgcn_mfma_f32_16x16x32_bf16(vf, pf[0][kh], Oacc[0][dt], 0, 0, 0);
                Oacc[1][dt] = __builtin_amdgcn_mfma_f32_16x16x32_bf16(vf, pf[1][kh], Oacc[1][dt], 0, 0, 0);
            }
        __builtin_amdgcn_s_setprio(0);
        asm volatile("s_waitcnt lgkmcnt(0)" ::: "memory");
        __builtin_amdgcn_s_barrier();
        cur ^= 1;
    }
#undef STAGE_K
#undef STAGE_V

    // lambda
    float sl1 = 0.f, sl2 = 0.f;
    for (int i = 0; i < 64; i++) { sl1 += lq1[i] * lk1[i]; sl2 += lq2[i] * lk2[i]; }
    const float lam = expf(sl1) - expf(sl2) + LAMBDA_INIT;

    // epilogue: diff, LN over 128 dims (lane group), direct M write
    const float i1 = 1.f / den[0];
    const float i2 = lam / den[1];
    float S1 = 0.f, S2 = 0.f;
#pragma unroll
    for (int dt = 0; dt < 8; dt++)
#pragma unroll
        for (int r = 0; r < 4; r++) {
            float v = Oacc[0][dt][r] * i1 - Oacc[1][dt][r] * i2;
            S1 += v; S2 += v * v;
        }
    S1 += __shfl_xor(S1, 16); S1 += __shfl_xor(S1, 32);
    S2 += __shfl_xor(S2, 16); S2 += __shfl_xor(S2, 32);
    const float mu = S1 * (1.f / 128.f);
    const float var = S2 * (1.f / 128.f) - mu * mu;
    const float rs = rsqrtf(var + 1e-5f) * ONE_MINUS_LI;

    const int R = h * 128 + (q0 >> 4) + w;  // same for whole wave
    u16* drow = Mg + (size_t)R * 2048 + q16 * 128;
#pragma unroll
    for (int dt = 0; dt < 8; dt++) {
        float v0 = (Oacc[0][dt][0] * i1 - Oacc[1][dt][0] * i2 - mu) * rs;
        float v1 = (Oacc[0][dt][1] * i1 - Oacc[1][dt][1] * i2 - mu) * rs;
        float v2 = (Oacc[0][dt][2] * i1 - Oacc[1][dt][2] * i2 - mu) * rs;
        float v3 = (Oacc[0][dt][3] * i1 - Oacc[1][dt][3] * i2 - mu) * rs;
        uint2 o;
        o.x = pkbf(v0, v1);
        o.y = pkbf(v2, v3);
        *(uint2*)(drow + dt * 16 + 4 * g) = o;
    }
}

extern "C" void kernel_launch(void* const* d_in, const int* in_sizes, int n_in,
                              void* d_out, int out_size, void* d_ws, size_t ws_size,
                              hipStream_t stream) {
    (void)in_sizes; (void)n_in; (void)out_size; (void)ws_size;
    const float* x = (const float*)d_in[0];
    const float* Wq = (const float*)d_in[1];
    const float* Wk = (const float*)d_in[2];
    const float* Wv = (const float*)d_in[3];
    const float* Wo = (const float*)d_in[4];
    const float* lq1 = (const float*)d_in[5];
    const float* lk1 = (const float*)d_in[6];
    const float* lq2 = (const float*)d_in[7];
    const float* lk2 = (const float*)d_in[8];

    u16* ws = (u16*)d_ws;
    const size_t SZ = 2048u * 2048u;
    u16* xb = ws;
    u16* Wqt = ws + SZ;
    u16* Wkt = ws + 2 * SZ;
    u16* Wvt = ws + 3 * SZ;
    u16* Wot = ws + 4 * SZ;
    u16* Qb = ws + 5 * SZ;
    u16* Kb = ws + 6 * SZ;
    u16* Vtb = ws + 7 * SZ;
    u16* Mb = ws + 8 * SZ;

    cast_f32_bf16<<<4096, 256, 0, stream>>>(x, xb);
    transpose_cast4<<<dim3(64, 64, 4), dim3(32, 8), 0, stream>>>(Wq, Wk, Wv, Wo, Wqt, Wkt, Wvt, Wot);

    gemm_qkv<<<1536, 256, 0, stream>>>(xb, Wqt, Wkt, Wvt, Qb, Kb, Vtb);

    diff_attn<<<512, 256, 0, stream>>>(Qb, Kb, Vtb, Mb, lq1, lk1, lq2, lk2);

    gemm_out<<<512, 256, 0, stream>>>(Mb, Wot, (float*)d_out);
}

// Round 5
// 162.910 us; speedup vs baseline: 2.2397x; 1.0864x over previous
//
#include <hip/hip_runtime.h>
#include <hip/hip_bf16.h>

// DiffAttn forward, MI355X/gfx950. bf16 MFMA everywhere, f32 softmax/LN.
// ws layout (u16 units, SZ = 2048*2048):
//   xb, Wqt, Wkt, Wvt, Wot, Qb, Kb, Vtb, Mb  -> 9*8MB = 72MB

typedef unsigned short u16;
typedef __attribute__((ext_vector_type(4))) float f32x4;
typedef __attribute__((ext_vector_type(8))) short bf16x8;

#define LAMBDA_INIT  0.7836057665317954f
#define ONE_MINUS_LI 0.2163942334682046f
// Q scale = hd^-0.5 * log2(e): QK^T lands pre-scaled for exp2-based softmax
#define QSCALE 0.18033688011112042f

// raw v_exp_f32 (exp2 semantics); avoids glibc __exp2f macro collision
#define EXP2F(x) __builtin_amdgcn_exp2f(x)

__device__ __forceinline__ u16 f2bf(float f) {
    union { float f; unsigned u; } v; v.f = f;
    unsigned r = v.u + 0x7FFFu + ((v.u >> 16) & 1u);   // RNE
    return (u16)(r >> 16);
}

// packed f32x2 -> bf16x2 (compiler emits v_cvt_pk_bf16_f32)
__device__ __forceinline__ unsigned pkbf(float a, float b) {
    union { __hip_bfloat162 h; unsigned u; } c;
    c.h = __float22bfloat162_rn(make_float2(a, b));
    return c.u;
}

__device__ __forceinline__ void gld_lds16(const u16* g, u16* l) {
    __builtin_amdgcn_global_load_lds((const __attribute__((address_space(1))) void*)g,
                                     (__attribute__((address_space(3))) void*)l, 16, 0, 0);
}

// ---------------- cast x (f32 -> bf16), 4M elements ----------------
__global__ void cast_f32_bf16(const float* __restrict__ in, u16* __restrict__ out) {
    int i = (blockIdx.x * 256 + threadIdx.x) * 4;
    float4 v = *(const float4*)(in + i);
    uint2 o;
    o.x = pkbf(v.x, v.y);
    o.y = pkbf(v.z, v.w);
    *(uint2*)(out + i) = o;
}

// ---------------- transpose + cast 4x W (2048x2048 f32 -> Wt bf16 [n][k]) ----------------
// 64x64 tiles, 256 threads, float4 reads, uint4 packed writes.
__global__ void transpose_cast4(const float* __restrict__ W0, const float* __restrict__ W1,
                                const float* __restrict__ W2, const float* __restrict__ W3,
                                u16* __restrict__ O0, u16* __restrict__ O1,
                                u16* __restrict__ O2, u16* __restrict__ O3) {
    __shared__ float tile[64][65];
    const int z = blockIdx.z;
    const float* W = z == 0 ? W0 : z == 1 ? W1 : z == 2 ? W2 : W3;
    u16* Wt = z == 0 ? O0 : z == 1 ? O1 : z == 2 ? O2 : O3;
    const int c0 = blockIdx.x * 64, r0 = blockIdx.y * 64;
    const int t = threadIdx.x;
    const int lr = t >> 2, lc = (t & 3) << 4;
#pragma unroll
    for (int jj = 0; jj < 4; jj++) {
        float4 v = *(const float4*)(W + (size_t)(r0 + lr) * 2048 + c0 + lc + 4 * jj);
        tile[lr][lc + 4 * jj + 0] = v.x;
        tile[lr][lc + 4 * jj + 1] = v.y;
        tile[lr][lc + 4 * jj + 2] = v.z;
        tile[lr][lc + 4 * jj + 3] = v.w;
    }
    __syncthreads();
    const int oc = t >> 2, op = (t & 3) << 4;
    uint ou[8];
#pragma unroll
    for (int k = 0; k < 8; k++)
        ou[k] = pkbf(tile[op + 2 * k][oc], tile[op + 2 * k + 1][oc]);
    u16* dst = Wt + (size_t)(c0 + oc) * 2048 + r0 + op;
    *(uint4*)(dst) = *(uint4*)&ou[0];
    *(uint4*)(dst + 8) = *(uint4*)&ou[4];
}

// ---------------- GEMM core: C[m][n] = scale * sum_k A[m][k]*B[n][k], all dims 2048 ----------------
// 128x64 tile, BK=64, 4 waves (each 32x64), dbuf gld_lds + XOR swizzle, counted vmcnt. 48KB LDS -> 3 blocks/CU.
template <int OUT_F32>
__device__ __forceinline__ void gemm_core(const u16* __restrict__ A, const u16* __restrict__ B,
                                          void* __restrict__ Cout, float scale, int m0, int n0) {
    __shared__ __align__(16) u16 As[2][128 * 64];
    __shared__ __align__(16) u16 Bs[2][64 * 64];
    const int tid = threadIdx.x;
    const int lane = tid & 63, w = tid >> 6;
    const int q16 = lane & 15, g = lane >> 4;
    const int sw = q16 & 7;
    const f32x4 fzero = {0.f, 0.f, 0.f, 0.f};
    f32x4 acc[2][4];
#pragma unroll
    for (int m = 0; m < 2; m++)
#pragma unroll
        for (int n = 0; n < 4; n++) acc[m][n] = fzero;

#define STG(buf, kb)                                                                 \
    {                                                                                \
        _Pragma("unroll") for (int p = 0; p < 4; p++) {                              \
            int s = p * 256 + tid;  /* A: 1024 granules */                           \
            int row = s >> 3, sg = (s ^ row) & 7;                                    \
            gld_lds16(A + (size_t)(m0 + row) * 2048 + (kb) + sg * 8, As[buf] + s * 8); \
        }                                                                            \
        _Pragma("unroll") for (int p = 0; p < 2; p++) {                              \
            int s = p * 256 + tid;  /* B: 512 granules */                            \
            int row = s >> 3, sg = (s ^ row) & 7;                                    \
            gld_lds16(B + (size_t)(n0 + row) * 2048 + (kb) + sg * 8, Bs[buf] + s * 8); \
        }                                                                            \
    }

    STG(0, 0);
    int cur = 0;
    for (int kb = 0; kb < 2048; kb += 64) {
        if (kb + 64 < 2048) {
            STG(cur ^ 1, kb + 64);
            asm volatile("s_waitcnt vmcnt(6)" ::: "memory");
        } else {
            asm volatile("s_waitcnt vmcnt(0)" ::: "memory");
        }
        __builtin_amdgcn_s_barrier();
        bf16x8 af[2][2], bfr[4][2];
#pragma unroll
        for (int m = 0; m < 2; m++) {
            const u16* ar = As[cur] + (w * 32 + m * 16 + q16) * 64;
            af[m][0] = *(const bf16x8*)(ar + 8 * (g ^ sw));
            af[m][1] = *(const bf16x8*)(ar + 8 * ((4 + g) ^ sw));
        }
#pragma unroll
        for (int n = 0; n < 4; n++) {
            const u16* br = Bs[cur] + (n * 16 + q16) * 64;
            bfr[n][0] = *(const bf16x8*)(br + 8 * (g ^ sw));
            bfr[n][1] = *(const bf16x8*)(br + 8 * ((4 + g) ^ sw));
        }
        __builtin_amdgcn_s_setprio(1);
#pragma unroll
        for (int m = 0; m < 2; m++)
#pragma unroll
            for (int n = 0; n < 4; n++) {
                acc[m][n] = __builtin_amdgcn_mfma_f32_16x16x32_bf16(af[m][0], bfr[n][0], acc[m][n], 0, 0, 0);
                acc[m][n] = __builtin_amdgcn_mfma_f32_16x16x32_bf16(af[m][1], bfr[n][1], acc[m][n], 0, 0, 0);
            }
        __builtin_amdgcn_s_setprio(0);
        asm volatile("s_waitcnt lgkmcnt(0)" ::: "memory");
        __builtin_amdgcn_s_barrier();
        cur ^= 1;
    }
#pragma unroll
    for (int m = 0; m < 2; m++)
#pragma unroll
        for (int n = 0; n < 4; n++) {
            int row = m0 + w * 32 + m * 16 + 4 * g;
            int col = n0 + n * 16 + q16;
#pragma unroll
            for (int r = 0; r < 4; r++) {
                float v = acc[m][n][r] * scale;
                if (OUT_F32) ((float*)Cout)[(size_t)(row + r) * 2048 + col] = v;
                else         ((u16*)Cout)[(size_t)(row + r) * 2048 + col] = f2bf(v);
            }
        }
#undef STG
}

// fused Q/K/V projections: 1536 blocks (3 GEMMs x 512 tiles of 128x64)
__global__ __launch_bounds__(256, 3) void gemm_qkv(const u16* __restrict__ xb,
                                                   const u16* __restrict__ Wqt, const u16* __restrict__ Wkt,
                                                   const u16* __restrict__ Wvt,
                                                   u16* __restrict__ Qb, u16* __restrict__ Kb,
                                                   u16* __restrict__ Vtb) {
    const int id = blockIdx.x;
    const int ord = (id & 7) * 192 + (id >> 3);   // bijective XCD chunking (1536 % 8 == 0)
    const int which = ord / 512, r = ord & 511;
    const int m0 = (r & 15) * 128, n0 = (r >> 4) * 64;
    const u16 *A, *B; u16* C; float sc;
    if (which == 0)      { A = xb;  B = Wqt; C = Qb;  sc = QSCALE; }
    else if (which == 1) { A = xb;  B = Wkt; C = Kb;  sc = 1.f; }
    else                 { A = Wvt; B = xb;  C = Vtb; sc = 1.f; }
    gemm_core<0>(A, B, C, sc, m0, n0);
}

// final projection: 512 blocks
__global__ __launch_bounds__(256, 3) void gemm_out(const u16* __restrict__ Mb, const u16* __restrict__ Wot,
                                                   float* __restrict__ out) {
    const int id = blockIdx.x;
    const int ord = (id & 7) * 64 + (id >> 3);
    const int m0 = (ord & 15) * 128, n0 = (ord >> 4) * 64;
    gemm_core<1>(Mb, Wot, out, 1.f, m0, n0);
}

// ---------------- fused dual-stream causal flash attention + diff + subLN + scatter to M ----------------
// grid 512 1D. Per-XCD balanced block remap: sizes ordered (A,33-A) pairs so both
// natural CU-fill patterns give 33 tile-iters per CU. No-max softmax (exp2 raw, bounded).
// Qb,Kb: [2048][2048] bf16 (Q pre-scaled by hd^-0.5*log2e). Vt[c][t] = V[t][c].
// M[h*128 + t/16][(t%16)*128 + d] = LN(O1/l1 - lam*O2/l2) * (1-LAMBDA_INIT)
__global__ __launch_bounds__(256, 2) void diff_attn(const u16* __restrict__ Qg, const u16* __restrict__ Kg,
                                                    const u16* __restrict__ Vg, u16* __restrict__ Mg,
                                                    const float* __restrict__ lq1, const float* __restrict__ lk1,
                                                    const float* __restrict__ lq2, const float* __restrict__ lk2) {
    __shared__ __align__(16) u16 smem[40960];   // 80 KB -> 2 blocks/CU
    const int tid = threadIdx.x;
    const int lane = tid & 63, w = tid >> 6;
    const int q16 = lane & 15, g = lane >> 4;
    const int sw = q16 & 7;
    const int id = blockIdx.x;
    // balanced remap: XCD xcd, pair p, parity o. A(p) = 32-p (p<16) else p-15.
    const int xcd = id & 7, jj = id >> 3;
    const int p = jj >> 1, o = jj & 1;
    const int A = (p < 16) ? (32 - p) : (p - 15);
    const int s = o ? (33 - A) : A;   // tile count for this block, 1..32
    const int qi = s - 1;
    const int h = (xcd << 1) | o;
    const int q0 = qi * 64;
    const int qg = q0 + 16 * w + q16;

    u16* Kb0 = smem;
    u16* Vb0 = smem + 8192;
    u16* Kb1 = smem + 16384;
    u16* Vb1 = smem + 24576;
    u16* Pw = smem + 32768 + w * 2048;  // [2 streams][16 q][64 k]

    bf16x8 qf[2][2];
#pragma unroll
    for (int st = 0; st < 2; st++)
#pragma unroll
        for (int db = 0; db < 2; db++)
            qf[st][db] = *(const bf16x8*)(Qg + (size_t)qg * 2048 + 128 * h + 64 * st + 32 * db + 8 * g);

#define STAGE_K(dst, kb)                                                         \
    {                                                                            \
        _Pragma("unroll") for (int p2 = 0; p2 < 4; p2++) {                       \
            int s2 = p2 * 256 + tid;                                             \
            int row = s2 >> 4, gc = s2 & 15;                                     \
            int sg = (gc & 8) | ((gc ^ row) & 7);                                \
            gld_lds16(Kg + (size_t)((kb) + row) * 2048 + 128 * h + sg * 8, (dst) + s2 * 8); \
        }                                                                        \
    }
#define STAGE_V(dst, kb)                                                         \
    {                                                                            \
        _Pragma("unroll") for (int p2 = 0; p2 < 4; p2++) {                       \
            int s2 = p2 * 256 + tid;                                             \
            int row = s2 >> 3, sg = (s2 ^ row) & 7;                              \
            gld_lds16(Vg + (size_t)(128 * h + row) * 2048 + (kb) + sg * 8, (dst) + s2 * 8); \
        }                                                                        \
    }

    const f32x4 fzero = {0.f, 0.f, 0.f, 0.f};
    f32x4 Oacc[2][8];
#pragma unroll
    for (int st = 0; st < 2; st++)
#pragma unroll
        for (int dt = 0; dt < 8; dt++) Oacc[st][dt] = fzero;
    float den[2] = {0.f, 0.f};   // per-lane partial denominators; reduced in epilogue

    const int nt = qi + 1;
    STAGE_K(Kb0, 0);
    STAGE_V(Vb0, 0);
    int cur = 0;
    for (int t = 0; t < nt; t++) {
        const int kb = t * 64;
        const u16* Ks = cur ? Kb1 : Kb0;
        const u16* Vs = cur ? Vb1 : Vb0;
        if (t + 1 < nt) {
            STAGE_K(cur ? Kb0 : Kb1, kb + 64);
            STAGE_V(cur ? Vb0 : Vb1, kb + 64);
            asm volatile("s_waitcnt vmcnt(8)" ::: "memory");
        } else {
            asm volatile("s_waitcnt vmcnt(0)" ::: "memory");
        }
        __builtin_amdgcn_s_barrier();

        // QK^T (S^T): D[k][q], both streams
        f32x4 sc[2][4];
        __builtin_amdgcn_s_setprio(1);
#pragma unroll
        for (int st = 0; st < 2; st++)
#pragma unroll
            for (int kt = 0; kt < 4; kt++) {
                const u16* kr = Ks + (kt * 16 + q16) * 128;
                bf16x8 kf0 = *(const bf16x8*)(kr + 8 * (st * 8 + (g ^ sw)));
                bf16x8 kf1 = *(const bf16x8*)(kr + 8 * (st * 8 + ((4 + g) ^ sw)));
                f32x4 a = __builtin_amdgcn_mfma_f32_16x16x32_bf16(kf0, qf[st][0], fzero, 0, 0, 0);
                a = __builtin_amdgcn_mfma_f32_16x16x32_bf16(kf1, qf[st][1], a, 0, 0, 0);
                sc[st][kt] = a;
            }
        __builtin_amdgcn_s_setprio(0);

        const bool last = (t == nt - 1);
        // no-max softmax: P = exp2(S) raw (bounded), mask via select-to-zero on diag tile
#pragma unroll
        for (int st = 0; st < 2; st++) {
            u16* Pst = Pw + st * 1024;
            float dl = 0.f;
#pragma unroll
            for (int kt = 0; kt < 4; kt++) {
                float p0 = EXP2F(sc[st][kt][0]);
                float p1 = EXP2F(sc[st][kt][1]);
                float p2 = EXP2F(sc[st][kt][2]);
                float p3 = EXP2F(sc[st][kt][3]);
                if (last) {
                    const int kgi = kb + kt * 16 + 4 * g;
                    p0 = (kgi + 0 <= qg) ? p0 : 0.f;
                    p1 = (kgi + 1 <= qg) ? p1 : 0.f;
                    p2 = (kgi + 2 <= qg) ? p2 : 0.f;
                    p3 = (kgi + 3 <= qg) ? p3 : 0.f;
                }
                dl += (p0 + p1) + (p2 + p3);
                uint2 pr;
                pr.x = pkbf(p0, p1);
                pr.y = pkbf(p2, p3);
                *(uint2*)(Pst + q16 * 64 + ((kt * 16 + 4 * g) ^ (8 * sw))) = pr;
            }
            den[st] += dl;
        }

        // PV: O^T = V^T x P^T ; V fragments shared by both streams
        bf16x8 pf[2][2];
#pragma unroll
        for (int st = 0; st < 2; st++)
#pragma unroll
            for (int kh = 0; kh < 2; kh++)
                pf[st][kh] = *(const bf16x8*)(Pw + st * 1024 + q16 * 64 + ((kh * 32 + 8 * g) ^ (8 * sw)));
        __builtin_amdgcn_s_setprio(1);
#pragma unroll
        for (int kh = 0; kh < 2; kh++)
#pragma unroll
            for (int dt = 0; dt < 8; dt++) {
                bf16x8 vf = *(const bf16x8*)(Vs + (dt * 16 + q16) * 64 + 8 * ((kh * 4 + g) ^ sw));
                Oacc[0][dt] = __builtin_amdgcn_mfma_f32_16x16x32_bf16(vf, pf[0][kh], Oacc[0][dt], 0, 0, 0);
                Oacc[1][dt] = __builtin_amdgcn_mfma_f32_16x16x32_bf16(vf, pf[1][kh], Oacc[1][dt], 0, 0, 0);
            }
        __builtin_amdgcn_s_setprio(0);
        asm volatile("s_waitcnt lgkmcnt(0)" ::: "memory");
        __builtin_amdgcn_s_barrier();
        cur ^= 1;
    }
#undef STAGE_K
#undef STAGE_V

    // lambda
    float sl1 = 0.f, sl2 = 0.f;
    for (int i = 0; i < 64; i++) { sl1 += lq1[i] * lk1[i]; sl2 += lq2[i] * lk2[i]; }
    const float lam = expf(sl1) - expf(sl2) + LAMBDA_INIT;

    // epilogue: reduce denominators across the 4-lane q-group, diff, LN over 128 dims, M write
    float d0 = den[0], d1 = den[1];
    d0 += __shfl_xor(d0, 16); d0 += __shfl_xor(d0, 32);
    d1 += __shfl_xor(d1, 16); d1 += __shfl_xor(d1, 32);
    const float i1 = 1.f / d0;
    const float i2 = lam / d1;
    float S1 = 0.f, S2 = 0.f;
#pragma unroll
    for (int dt = 0; dt < 8; dt++)
#pragma unroll
        for (int r = 0; r < 4; r++) {
            float v = Oacc[0][dt][r] * i1 - Oacc[1][dt][r] * i2;
            S1 += v; S2 += v * v;
        }
    S1 += __shfl_xor(S1, 16); S1 += __shfl_xor(S1, 32);
    S2 += __shfl_xor(S2, 16); S2 += __shfl_xor(S2, 32);
    const float mu = S1 * (1.f / 128.f);
    const float var = S2 * (1.f / 128.f) - mu * mu;
    const float rs = rsqrtf(var + 1e-5f) * ONE_MINUS_LI;

    const int R = h * 128 + (q0 >> 4) + w;  // same for whole wave
    u16* drow = Mg + (size_t)R * 2048 + q16 * 128;
#pragma unroll
    for (int dt = 0; dt < 8; dt++) {
        float v0 = (Oacc[0][dt][0] * i1 - Oacc[1][dt][0] * i2 - mu) * rs;
        float v1 = (Oacc[0][dt][1] * i1 - Oacc[1][dt][1] * i2 - mu) * rs;
        float v2 = (Oacc[0][dt][2] * i1 - Oacc[1][dt][2] * i2 - mu) * rs;
        float v3 = (Oacc[0][dt][3] * i1 - Oacc[1][dt][3] * i2 - mu) * rs;
        uint2 oo;
        oo.x = pkbf(v0, v1);
        oo.y = pkbf(v2, v3);
        *(uint2*)(drow + dt * 16 + 4 * g) = oo;
    }
}

extern "C" void kernel_launch(void* const* d_in, const int* in_sizes, int n_in,
                              void* d_out, int out_size, void* d_ws, size_t ws_size,
                              hipStream_t stream) {
    (void)in_sizes; (void)n_in; (void)out_size; (void)ws_size;
    const float* x = (const float*)d_in[0];
    const float* Wq = (const float*)d_in[1];
    const float* Wk = (const float*)d_in[2];
    const float* Wv = (const float*)d_in[3];
    const float* Wo = (const float*)d_in[4];
    const float* lq1 = (const float*)d_in[5];
    const float* lk1 = (const float*)d_in[6];
    const float* lq2 = (const float*)d_in[7];
    const float* lk2 = (const float*)d_in[8];

    u16* ws = (u16*)d_ws;
    const size_t SZ = 2048u * 2048u;
    u16* xb = ws;
    u16* Wqt = ws + SZ;
    u16* Wkt = ws + 2 * SZ;
    u16* Wvt = ws + 3 * SZ;
    u16* Wot = ws + 4 * SZ;
    u16* Qb = ws + 5 * SZ;
    u16* Kb = ws + 6 * SZ;
    u16* Vtb = ws + 7 * SZ;
    u16* Mb = ws + 8 * SZ;

    cast_f32_bf16<<<4096, 256, 0, stream>>>(x, xb);
    transpose_cast4<<<dim3(32, 32, 4), 256, 0, stream>>>(Wq, Wk, Wv, Wo, Wqt, Wkt, Wvt, Wot);

    gemm_qkv<<<1536, 256, 0, stream>>>(xb, Wqt, Wkt, Wvt, Qb, Kb, Vtb);

    diff_attn<<<512, 256, 0, stream>>>(Qb, Kb, Vtb, Mb, lq1, lk1, lq2, lk2);

    gemm_out<<<512, 256, 0, stream>>>(Mb, Wot, (float*)d_out);
}